// Round 14
// baseline (568.936 us; speedup 1.0000x reference)
//
#include <hip/hip_runtime.h>
#include <hip/hip_bf16.h>

#define DIM 2048
#define NHEADS 16
#define HEAD_DIM 128
#define HIDDEN 2048
#define SEQ 4096
#define BATCH 2
#define BT (BATCH * SEQ)        // 8192
#define NSEG 64
#define SEGLEN (SEQ / NSEG)     // 64
#define N_GATE (3 * HIDDEN)     // 6144

typedef __bf16 bf16_t;
typedef __bf16 bf16x8 __attribute__((ext_vector_type(8)));
typedef __bf16 bf16x4_t __attribute__((ext_vector_type(4)));
typedef __bf16 bf16x2_t __attribute__((ext_vector_type(2)));
typedef float f32x4 __attribute__((ext_vector_type(4)));

__device__ __forceinline__ void gload_lds16(const void* g, void* l) {
  __builtin_amdgcn_global_load_lds(
      (const __attribute__((address_space(1))) void*)g,
      (__attribute__((address_space(3))) void*)l, 16, 0, 0);
}

#define MEMFENCE asm volatile("" ::: "memory")
#define BAR do { MEMFENCE; __builtin_amdgcn_s_barrier(); MEMFENCE; } while (0)
#define VMCNT(n) asm volatile("s_waitcnt vmcnt(" #n ")" ::: "memory")

// ---------------- prep: f32 -> bf16 convert (vectorized) ----------------
__global__ void cvt_f32_bf16(const float* __restrict__ src, bf16_t* __restrict__ dst, int n4) {
  int i = blockIdx.x * blockDim.x + threadIdx.x;
  if (i >= n4) return;
  float4 v = reinterpret_cast<const float4*>(src)[i];
  bf16x4_t o;
  o[0] = (bf16_t)v.x; o[1] = (bf16_t)v.y; o[2] = (bf16_t)v.z; o[3] = (bf16_t)v.w;
  reinterpret_cast<bf16x4_t*>(dst)[i] = o;
}

// ------- f gate (fp32, precision-critical) + fused x -> bf16 conversion -------
__global__ void fgate_cvt(const float* __restrict__ x, const float* __restrict__ Wg,
                          const float* __restrict__ bg, float* __restrict__ fout,
                          bf16_t* __restrict__ xb) {
  int idx = blockIdx.x * 256 + threadIdx.x;
  int bt = idx >> 4, h = idx & 15;
  const float* xr = x + (size_t)bt * DIM;
  const float* wr = Wg + (size_t)h * DIM;
  float acc = 0.f;
  for (int k = 0; k < DIM; k += 4) {
    float4 xv = *reinterpret_cast<const float4*>(xr + k);
    float4 wv = *reinterpret_cast<const float4*>(wr + k);
    acc = fmaf(xv.x, wv.x, acc);
    acc = fmaf(xv.y, wv.y, acc);
    acc = fmaf(xv.z, wv.z, acc);
    acc = fmaf(xv.w, wv.w, acc);
  }
  acc += bg[h];
  fout[idx] = 1.f / (1.f + expf(-acc));
  const float* xs = xr + h * HEAD_DIM;
  bf16_t* xd = xb + (size_t)bt * DIM + h * HEAD_DIM;
#pragma unroll
  for (int k = 0; k < HEAD_DIM; k += 8) {
    float4 a = *reinterpret_cast<const float4*>(xs + k);
    float4 b = *reinterpret_cast<const float4*>(xs + k + 4);
    bf16x8 o;
    o[0] = (bf16_t)a.x; o[1] = (bf16_t)a.y; o[2] = (bf16_t)a.z; o[3] = (bf16_t)a.w;
    o[4] = (bf16_t)b.x; o[5] = (bf16_t)b.y; o[6] = (bf16_t)b.z; o[7] = (bf16_t)b.w;
    *reinterpret_cast<bf16x8*>(xd + k) = o;
  }
}

// ------------- 128x128 tile, BK=64, 2 blocks/CU cross-block-overlap GEMM -------------
// C = A * B^T, both row-major with K contiguous; K = 2048 (KT = 32 K-tiles).
// r14 change (one variable vs r8): independent barrier domains per CU.
//   r7-r9 all pinned at MfmaUtil ~30% with ONE 512-thr block/CU (128KB LDS): every
//   barrier/vmcnt stall is CU-global. This kernel: 128^2 tile, 256 thr (4 waves of
//   64x64), LDS 64KB -> 2 blocks/CU. Same 8 waves/CU, but two independent barrier
//   groups: block A's vmcnt(0) drain is covered by block B's MFMA (m97's 912 TF
//   came from exactly this implicit cross-block overlap, m114).
// Schedule = simple m97 loop (proven): read frags(t) -> stage tile(t+1) -> MFMA ->
//   vmcnt(0) -> BAR. One barrier/tile. W-A-R: stage(t+1) overwrites slot last read
//   at tile t-1, >=1 BAR back. Visibility: vmcnt(0)+BAR before reads.
// LDS: A,B = [128 rows][64 cols] per slot; 128-B rows; chunk c of row r stored at
//   slot c ^ (r&7) (0-conflict PMC r5-r9); source pre-swizzled (rule 21).

__device__ __forceinline__ void stage_u(const bf16_t* __restrict__ G, int grow0, int kc,
                                        bf16_t* region, int u, int tid) {
  const int row = u * 32 + (tid >> 3);                 // region row (32 rows/unit)
  const int c = (tid & 7) ^ ((tid >> 3) & 7);          // logical chunk for stored slot
  gload_lds16(G + (size_t)(grow0 + row) * 2048 + kc + c * 8,
              region + (size_t)(u * 32 + (tid >> 6) * 8) * 64);  // wave-uniform + lane*16B
}

#define FRAG8(ptr, row, fo) (*reinterpret_cast<const bf16x8*>(&(ptr)[(size_t)(row) * 64 + (fo)]))

template <int MODE>
__global__ __launch_bounds__(256, 2)
void gemm128(const bf16_t* __restrict__ A, const bf16_t* __restrict__ B,
             const float* __restrict__ bias,
             bf16_t* __restrict__ Oi, bf16_t* __restrict__ Ot, bf16_t* __restrict__ Oo,
             float* __restrict__ Of, int tiles_n) {
  __shared__ __align__(16) bf16_t As[2][128 * 64];
  __shared__ __align__(16) bf16_t Bs[2][128 * 64];
  constexpr int KT = 32;  // 2048 / 64

  const int tid = threadIdx.x;
  const int lane = tid & 63;
  const int wid = tid >> 6;
  const int nwg = gridDim.x, bid = blockIdx.x;
  const int swz = (bid & 7) * (nwg >> 3) + (bid >> 3);      // bijective (nwg%8==0)
  const int tm = swz / tiles_n, tn = swz - tm * tiles_n;
  const int brow = tm * 128, bcol = tn * 128;
  const int wm = wid >> 1, wn = wid & 1;                     // 2x2 waves; wave out 64x64
  const int rl = lane & 15, qw = lane >> 4;
  const int fo0 = ((qw ^ (rl & 7)) << 3);                    // kh0 swizzled chunk offset
  const int fo1 = fo0 ^ 32;                                  // kh1 chunk = +4 -> ^32 elems

  f32x4 acc[4][4] = {};

  // prologue: tile0 A+B (8 loads/thread), drain, barrier
#pragma unroll
  for (int u = 0; u < 4; ++u) stage_u(B, bcol, 0, &Bs[0][0], u, tid);
#pragma unroll
  for (int u = 0; u < 4; ++u) stage_u(A, brow, 0, &As[0][0], u, tid);
  VMCNT(0);
  BAR;

  for (int t = 0; t < KT; ++t) {
    const int s = t & 1, ns = s ^ 1;
    const int kc1 = (t + 1) * 64;
    const bool st1 = (t + 1) < KT;
    const bf16_t* Ar = &As[s][0];
    const bf16_t* Br = &Bs[s][0];
    bf16x8 afr[2][4], bfr[2][4];

#pragma unroll
    for (int mi = 0; mi < 4; ++mi) {
      afr[0][mi] = FRAG8(Ar, wm * 64 + mi * 16 + rl, fo0);
      afr[1][mi] = FRAG8(Ar, wm * 64 + mi * 16 + rl, fo1);
    }
#pragma unroll
    for (int ni = 0; ni < 4; ++ni) {
      bfr[0][ni] = FRAG8(Br, wn * 64 + ni * 16 + rl, fo0);
      bfr[1][ni] = FRAG8(Br, wn * 64 + ni * 16 + rl, fo1);
    }
    if (st1) {
#pragma unroll
      for (int u = 0; u < 4; ++u) stage_u(B, bcol, kc1, &Bs[ns][0], u, tid);
#pragma unroll
      for (int u = 0; u < 4; ++u) stage_u(A, brow, kc1, &As[ns][0], u, tid);
    }
    __builtin_amdgcn_s_setprio(1);
#pragma unroll
    for (int mi = 0; mi < 4; ++mi)
#pragma unroll
      for (int ni = 0; ni < 4; ++ni)
        acc[mi][ni] = __builtin_amdgcn_mfma_f32_16x16x32_bf16(afr[0][mi], bfr[0][ni], acc[mi][ni], 0, 0, 0);
#pragma unroll
    for (int mi = 0; mi < 4; ++mi)
#pragma unroll
      for (int ni = 0; ni < 4; ++ni)
        acc[mi][ni] = __builtin_amdgcn_mfma_f32_16x16x32_bf16(afr[1][mi], bfr[1][ni], acc[mi][ni], 0, 0, 0);
    __builtin_amdgcn_s_setprio(0);
    if (st1) { VMCNT(0); }   // tile t+1 landed (cross-block overlap covers the drain)
    BAR;
  }

  // epilogue. C/D layout: col = lane&15, row = (lane>>4)*4 + q  [m89/m91]
  const int crow0 = brow + wm * 64;
  const int ccol0 = bcol + wn * 64;
  if (MODE == 0) {
    const int section = bcol >> 11;  // 128-tile lies fully inside one 2048-section
    bf16_t* dst = (section == 0) ? Oi : ((section == 1) ? Ot : Oo);
#pragma unroll
    for (int mi = 0; mi < 4; ++mi)
#pragma unroll
      for (int ni = 0; ni < 4; ++ni) {
        int gcol = ccol0 + ni * 16 + rl;
        int col = gcol & 2047;
        float bv = bias[gcol];
#pragma unroll
        for (int qq = 0; qq < 4; ++qq) {
          int row = crow0 + mi * 16 + qw * 4 + qq;
          float v = acc[mi][ni][qq] + bv;
          float aout;
          if (section == 0)      aout = 1.f / (1.f + __expf(-v));
          else if (section == 1) aout = tanhf(v);
          else                   aout = v;
          dst[(size_t)row * HIDDEN + col] = (bf16_t)aout;
        }
      }
  } else {
#pragma unroll
    for (int mi = 0; mi < 4; ++mi)
#pragma unroll
      for (int ni = 0; ni < 4; ++ni) {
        int col = ccol0 + ni * 16 + rl;
        float bv = bias[col];
#pragma unroll
        for (int qq = 0; qq < 4; ++qq) {
          int row = crow0 + mi * 16 + qw * 4 + qq;
          Of[(size_t)row * DIM + col] = acc[mi][ni][qq] + bv;
        }
      }
  }
}

// ---------------- segmented scan (x2-channel vectorized, G13) ----------------
__global__ void scan_pass1(const float* __restrict__ fg, const bf16_t* __restrict__ gi,
                           const bf16_t* __restrict__ gt, float* __restrict__ cend,
                           float* __restrict__ pseg) {
  int bx = blockIdx.x;
  int chblk = bx & 3, seg = (bx >> 2) & 63, b = bx >> 8;
  int chp = chblk * 256 + threadIdx.x;     // 0..1023
  int ch = chp * 2;
  int head = chp >> 6;
  float c0 = 0.f, c1 = 0.f, P = 1.f;
  size_t t0 = (size_t)b * SEQ + (size_t)seg * SEGLEN;
  for (int tt = 0; tt < SEGLEN; ++tt) {
    size_t bt = t0 + tt;
    float f = fg[bt * NHEADS + head];
    bf16x2_t iv = *reinterpret_cast<const bf16x2_t*>(&gi[bt * HIDDEN + ch]);
    bf16x2_t tv = *reinterpret_cast<const bf16x2_t*>(&gt[bt * HIDDEN + ch]);
    c0 = fmaf(f, c0, (float)iv[0] * (float)tv[0]);
    c1 = fmaf(f, c1, (float)iv[1] * (float)tv[1]);
    P *= f;
  }
  size_t o = ((size_t)b * NSEG + seg) * HIDDEN + ch;
  *reinterpret_cast<float2*>(&cend[o]) = make_float2(c0, c1);
  *reinterpret_cast<float2*>(&pseg[o]) = make_float2(P, P);
}

__global__ void scan_pass2(const float* __restrict__ cend, const float* __restrict__ pseg,
                           float* __restrict__ cin) {
  int idx = blockIdx.x * 256 + threadIdx.x;  // 4096
  int b = idx >> 11, ch = idx & 2047;
  float C = 0.f;
  for (int s = 0; s < NSEG; ++s) {
    size_t o = ((size_t)b * NSEG + s) * HIDDEN + ch;
    cin[o] = C;
    C = cend[o] + pseg[o] * C;
  }
}

__global__ void scan_pass3(const float* __restrict__ fg, const bf16_t* __restrict__ gi,
                           const bf16_t* __restrict__ gt, const bf16_t* __restrict__ go,
                           const float* __restrict__ cin, bf16_t* __restrict__ h) {
  int bx = blockIdx.x;
  int chblk = bx & 3, seg = (bx >> 2) & 63, b = bx >> 8;
  int chp = chblk * 256 + threadIdx.x;
  int ch = chp * 2;
  int head = chp >> 6;
  float2 cv = *reinterpret_cast<const float2*>(&cin[((size_t)b * NSEG + seg) * HIDDEN + ch]);
  float c0 = cv.x, c1 = cv.y;
  size_t t0 = (size_t)b * SEQ + (size_t)seg * SEGLEN;
  for (int tt = 0; tt < SEGLEN; ++tt) {
    size_t bt = t0 + tt;
    float f = fg[bt * NHEADS + head];
    bf16x2_t iv = *reinterpret_cast<const bf16x2_t*>(&gi[bt * HIDDEN + ch]);
    bf16x2_t tv = *reinterpret_cast<const bf16x2_t*>(&gt[bt * HIDDEN + ch]);
    bf16x2_t ov = *reinterpret_cast<const bf16x2_t*>(&go[bt * HIDDEN + ch]);
    c0 = fmaf(f, c0, (float)iv[0] * (float)tv[0]);
    c1 = fmaf(f, c1, (float)iv[1] * (float)tv[1]);
    bf16x2_t hv;
    hv[0] = (bf16_t)((float)ov[0] * tanhf(c0));
    hv[1] = (bf16_t)((float)ov[1] * tanhf(c1));
    *reinterpret_cast<bf16x2_t*>(&h[bt * HIDDEN + ch]) = hv;
  }
}

extern "C" void kernel_launch(void* const* d_in, const int* in_sizes, int n_in,
                              void* d_out, int out_size, void* d_ws, size_t ws_size,
                              hipStream_t stream) {
  const float* x  = (const float*)d_in[0];
  const float* Wg = (const float*)d_in[1];
  const float* bg = (const float*)d_in[2];
  const float* Wo = (const float*)d_in[3];
  const float* bo = (const float*)d_in[4];
  float* out = (float*)d_out;

  char* ws = (char*)d_ws;
  size_t off = 0;
  auto alloc = [&](size_t bytes) -> void* {
    void* p = ws + off;
    off += (bytes + 255) & ~(size_t)255;
    return p;
  };
  bf16_t* xb   = (bf16_t*)alloc((size_t)BT * DIM * 2);
  bf16_t* wgb  = (bf16_t*)alloc((size_t)N_GATE * DIM * 2);
  bf16_t* wob  = (bf16_t*)alloc((size_t)DIM * HIDDEN * 2);
  float*  fg   = (float*)alloc((size_t)BT * NHEADS * 4);
  bf16_t* gi   = (bf16_t*)alloc((size_t)BT * HIDDEN * 2);
  bf16_t* gt   = (bf16_t*)alloc((size_t)BT * HIDDEN * 2);
  bf16_t* go   = (bf16_t*)alloc((size_t)BT * HIDDEN * 2);
  bf16_t* hbuf = (bf16_t*)alloc((size_t)BT * HIDDEN * 2);
  float*  cend = (float*)alloc((size_t)BATCH * NSEG * HIDDEN * 4);
  float*  pseg = (float*)alloc((size_t)BATCH * NSEG * HIDDEN * 4);
  float*  cin  = (float*)alloc((size_t)BATCH * NSEG * HIDDEN * 4);
  (void)ws_size; (void)in_sizes; (void)n_in; (void)out_size;

  // weight converts (x-convert is fused into fgate_cvt)
  {
    int n4 = N_GATE * DIM / 4;
    cvt_f32_bf16<<<(n4 + 255) / 256, 256, 0, stream>>>(Wg + (size_t)NHEADS * DIM, wgb, n4);
  }
  {
    int n4 = DIM * HIDDEN / 4;
    cvt_f32_bf16<<<(n4 + 255) / 256, 256, 0, stream>>>(Wo, wob, n4);
  }

  // f gate in fp32 + fused x -> bf16
  fgate_cvt<<<(BT * NHEADS) / 256, 256, 0, stream>>>(x, Wg, bg, fg, xb);

  // gates GEMM: M=8192, N=6144, K=2048 -> 64x48 = 3072 tiles (2 blocks/CU)
  gemm128<0><<<3072, 256, 0, stream>>>(xb, wgb, bg + NHEADS, gi, gt, go, nullptr, 48);

  // segmented scan (x2-channel vectorized)
  scan_pass1<<<BATCH * NSEG * (HIDDEN / 512), 256, 0, stream>>>(fg, gi, gt, cend, pseg);
  scan_pass2<<<BATCH * HIDDEN / 256, 256, 0, stream>>>(cend, pseg, cin);
  scan_pass3<<<BATCH * NSEG * (HIDDEN / 512), 256, 0, stream>>>(fg, gi, gt, go, cin, hbuf);

  // output GEMM: M=8192, N=2048, K=2048 -> 64x16 = 1024 tiles
  gemm128<1><<<1024, 256, 0, stream>>>(hbuf, wob, bo, nullptr, nullptr, nullptr, out, 16);
}

// Round 15
// 520.000 us; speedup vs baseline: 1.0941x; 1.0941x over previous
//
#include <hip/hip_runtime.h>
#include <hip/hip_bf16.h>

#define DIM 2048
#define NHEADS 16
#define HEAD_DIM 128
#define HIDDEN 2048
#define SEQ 4096
#define BATCH 2
#define BT (BATCH * SEQ)        // 8192
#define NSEG 64
#define SEGLEN (SEQ / NSEG)     // 64
#define N_GATE (3 * HIDDEN)     // 6144

typedef __bf16 bf16_t;
typedef __bf16 bf16x8 __attribute__((ext_vector_type(8)));
typedef __bf16 bf16x4_t __attribute__((ext_vector_type(4)));
typedef float f32x4 __attribute__((ext_vector_type(4)));

__device__ __forceinline__ void gload_lds16(const void* g, void* l) {
  __builtin_amdgcn_global_load_lds(
      (const __attribute__((address_space(1))) void*)g,
      (__attribute__((address_space(3))) void*)l, 16, 0, 0);
}

#define MEMFENCE asm volatile("" ::: "memory")
#define BAR do { MEMFENCE; __builtin_amdgcn_s_barrier(); MEMFENCE; } while (0)
#define VMCNT(n) asm volatile("s_waitcnt vmcnt(" #n ")" ::: "memory")

// -------- merged weight converts: Wg-gates (6144x2048) + Wo (2048x2048) --------
__global__ void cvt_weights(const float* __restrict__ a, bf16_t* __restrict__ da, int n4a,
                            const float* __restrict__ b, bf16_t* __restrict__ db, int n4b) {
  int i = blockIdx.x * 256 + threadIdx.x;
  const float* s;
  bf16_t* d;
  if (i < n4a) { s = a + (size_t)i * 4; d = da + (size_t)i * 4; }
  else if (i < n4a + n4b) { int j = i - n4a; s = b + (size_t)j * 4; d = db + (size_t)j * 4; }
  else return;
  float4 v = *reinterpret_cast<const float4*>(s);
  bf16x4_t o;
  o[0] = (bf16_t)v.x; o[1] = (bf16_t)v.y; o[2] = (bf16_t)v.z; o[3] = (bf16_t)v.w;
  *reinterpret_cast<bf16x4_t*>(d) = o;
}

// ------- f gate (fp32, precision-critical) + fused x -> bf16 conversion -------
__global__ void fgate_cvt(const float* __restrict__ x, const float* __restrict__ Wg,
                          const float* __restrict__ bg, float* __restrict__ fout,
                          bf16_t* __restrict__ xb) {
  int idx = blockIdx.x * 256 + threadIdx.x;
  int bt = idx >> 4, h = idx & 15;
  const float* xr = x + (size_t)bt * DIM;
  const float* wr = Wg + (size_t)h * DIM;
  float acc = 0.f;
  for (int k = 0; k < DIM; k += 4) {
    float4 xv = *reinterpret_cast<const float4*>(xr + k);
    float4 wv = *reinterpret_cast<const float4*>(wr + k);
    acc = fmaf(xv.x, wv.x, acc);
    acc = fmaf(xv.y, wv.y, acc);
    acc = fmaf(xv.z, wv.z, acc);
    acc = fmaf(xv.w, wv.w, acc);
  }
  acc += bg[h];
  fout[idx] = 1.f / (1.f + expf(-acc));
  const float* xs = xr + h * HEAD_DIM;
  bf16_t* xd = xb + (size_t)bt * DIM + h * HEAD_DIM;
#pragma unroll
  for (int k = 0; k < HEAD_DIM; k += 8) {
    float4 a = *reinterpret_cast<const float4*>(xs + k);
    float4 b = *reinterpret_cast<const float4*>(xs + k + 4);
    bf16x8 o;
    o[0] = (bf16_t)a.x; o[1] = (bf16_t)a.y; o[2] = (bf16_t)a.z; o[3] = (bf16_t)a.w;
    o[4] = (bf16_t)b.x; o[5] = (bf16_t)b.y; o[6] = (bf16_t)b.z; o[7] = (bf16_t)b.w;
    *reinterpret_cast<bf16x8*>(xd + k) = o;
  }
}

// ------------- 256x256, BK=64, 2-slot dbuf, 4-phase single-barrier GEMM (r8) -------------
// Best of the r1-r14 structure sweep: 290us mode0 @ MfmaUtil 29.8, conflicts 0.
// (r1 m97-1buf=295, r9 sandwich=320, r10 32x32=313, r12 4-wave=583, r14 2-block=290+2xFETCH.)
// C = A * B^T, both row-major, K=2048 (KT=32). LDS per slot: A=[quarter][64][64],
// B=[256][64]; 128-B rows; chunk c of row r stored at c^(r&7) (0-conflict PMC),
// source pre-swizzled (rule 21). One barrier per phase; counted vmcnt ledger:
// entering tile t outstanding = [A(t+1)q0..q2, A(t)q3]; VMCNT(4)@p1; VMCNT(4)@p3
// drains B(t+1)x4. Tail: (KT-2,p3)=1, (KT-1,p1)=0.

__device__ __forceinline__ void stageA(const bf16_t* __restrict__ G, int brow, int kc,
                                       bf16_t* Aslot, int q, int wid, int lane) {
  const int rr = q * 64 + wid * 8;
  const int grow = brow + (wid >> 2) * 128 + q * 32 + (wid & 3) * 8 + (lane >> 3);
  const int gcol = kc + (((lane & 7) ^ (lane >> 3)) << 3);
  gload_lds16(G + (size_t)grow * 2048 + gcol, Aslot + (size_t)rr * 64);
}

__device__ __forceinline__ void stageB(const bf16_t* __restrict__ G, int bcol, int kc,
                                       bf16_t* Bslot, int j, int wid, int lane) {
  const int rr = (j >> 1) * 128 + (j & 1) * 64 + wid * 8;
  const int grow = bcol + rr + (lane >> 3);
  const int gcol = kc + (((lane & 7) ^ (lane >> 3)) << 3);
  gload_lds16(G + (size_t)grow * 2048 + gcol, Bslot + (size_t)rr * 64);
}

#define FRAG8(ptr, row, fo) (*reinterpret_cast<const bf16x8*>(&(ptr)[(size_t)(row) * 64 + (fo)]))

template <int MODE>
__global__ __launch_bounds__(512, 1)
void gemm256(const bf16_t* __restrict__ A, const bf16_t* __restrict__ B,
             const float* __restrict__ bias,
             bf16_t* __restrict__ Oi, bf16_t* __restrict__ Ot, bf16_t* __restrict__ Oo,
             float* __restrict__ Of, int tiles_n) {
  __shared__ __align__(16) bf16_t As[2][256 * 64];
  __shared__ __align__(16) bf16_t Bs[2][256 * 64];
  constexpr int KT = 32;

  const int tid = threadIdx.x;
  const int wid = tid >> 6, lane = tid & 63;
  const int nwg = gridDim.x, bid = blockIdx.x;
  const int swz = (bid & 7) * (nwg >> 3) + (bid >> 3);
  const int tm = swz / tiles_n, tn = swz - tm * tiles_n;
  const int brow = tm * 256, bcol = tn * 256;
  const int wm = wid >> 2, wn = wid & 3;
  const int rl = lane & 15, qw = lane >> 4;
  const int fo0 = ((qw ^ (rl & 7)) << 3);
  const int fo1 = fo0 ^ 32;
  const int brr = (wn >> 1) * 128 + (wn & 1) * 64;

  f32x4 acc[8][4] = {};

#pragma unroll
  for (int j = 0; j < 4; ++j) stageB(B, bcol, 0, &Bs[0][0], j, wid, lane);
#pragma unroll
  for (int qq = 0; qq < 4; ++qq) stageA(A, brow, 0, &As[0][0], qq, wid, lane);
#pragma unroll
  for (int qq = 0; qq < 3; ++qq) stageA(A, brow, 64, &As[1][0], qq, wid, lane);
  VMCNT(3);
  BAR;

  for (int t = 0; t < KT; ++t) {
    const int s = t & 1, ns = s ^ 1;
    const int kc1 = (t + 1) * 64, kc2 = (t + 2) * 64;
    const bool st1 = (t + 1) < KT, st2 = (t + 2) < KT;
    const bf16_t* Ar = &As[s][0];
    const bf16_t* Br = &Bs[s][0];
    bf16x8 bfr[2][4], af[2][2];

#define MFMA16(p)                                                                         \
  __builtin_amdgcn_s_setprio(1);                                                          \
  _Pragma("unroll")                                                                       \
  for (int mi = 0; mi < 2; ++mi)                                                          \
    _Pragma("unroll")                                                                     \
    for (int ni = 0; ni < 4; ++ni)                                                        \
      acc[(p)*2 + mi][ni] =                                                               \
          __builtin_amdgcn_mfma_f32_16x16x32_bf16(af[0][mi], bfr[0][ni], acc[(p)*2 + mi][ni], 0, 0, 0); \
  _Pragma("unroll")                                                                       \
  for (int mi = 0; mi < 2; ++mi)                                                          \
    _Pragma("unroll")                                                                     \
    for (int ni = 0; ni < 4; ++ni)                                                        \
      acc[(p)*2 + mi][ni] =                                                               \
          __builtin_amdgcn_mfma_f32_16x16x32_bf16(af[1][mi], bfr[1][ni], acc[(p)*2 + mi][ni], 0, 0, 0); \
  __builtin_amdgcn_s_setprio(0)

    // ---------- phase 0 ----------
#pragma unroll
    for (int ni = 0; ni < 4; ++ni) {
      bfr[0][ni] = FRAG8(Br, brr + ni * 16 + rl, fo0);
      bfr[1][ni] = FRAG8(Br, brr + ni * 16 + rl, fo1);
    }
#pragma unroll
    for (int mi = 0; mi < 2; ++mi) {
      af[0][mi] = FRAG8(Ar, 0 * 64 + wm * 32 + mi * 16 + rl, fo0);
      af[1][mi] = FRAG8(Ar, 0 * 64 + wm * 32 + mi * 16 + rl, fo1);
    }
    if (st1) { stageB(B, bcol, kc1, &Bs[ns][0], 0, wid, lane);
               stageB(B, bcol, kc1, &Bs[ns][0], 1, wid, lane); }
    BAR;
    MFMA16(0);

    // ---------- phase 1 ----------
#pragma unroll
    for (int mi = 0; mi < 2; ++mi) {
      af[0][mi] = FRAG8(Ar, 1 * 64 + wm * 32 + mi * 16 + rl, fo0);
      af[1][mi] = FRAG8(Ar, 1 * 64 + wm * 32 + mi * 16 + rl, fo1);
    }
    if (st1) { stageB(B, bcol, kc1, &Bs[ns][0], 2, wid, lane);
               stageB(B, bcol, kc1, &Bs[ns][0], 3, wid, lane); }
    if (t < KT - 1) { VMCNT(4); } else { VMCNT(0); }
    BAR;
    MFMA16(1);

    // ---------- phase 2 ----------
#pragma unroll
    for (int mi = 0; mi < 2; ++mi) {
      af[0][mi] = FRAG8(Ar, 2 * 64 + wm * 32 + mi * 16 + rl, fo0);
      af[1][mi] = FRAG8(Ar, 2 * 64 + wm * 32 + mi * 16 + rl, fo1);
    }
    if (st2) { stageA(A, brow, kc2, &As[s][0], 0, wid, lane);
               stageA(A, brow, kc2, &As[s][0], 1, wid, lane); }
    BAR;
    MFMA16(2);

    // ---------- phase 3 ----------
#pragma unroll
    for (int mi = 0; mi < 2; ++mi) {
      af[0][mi] = FRAG8(Ar, 3 * 64 + wm * 32 + mi * 16 + rl, fo0);
      af[1][mi] = FRAG8(Ar, 3 * 64 + wm * 32 + mi * 16 + rl, fo1);
    }
    if (st2) stageA(A, brow, kc2, &As[s][0], 2, wid, lane);
    if (st1) stageA(A, brow, kc1, &As[ns][0], 3, wid, lane);
    if (t < KT - 2) { VMCNT(4); }
    else if (t == KT - 2) { VMCNT(1); }
    BAR;
    MFMA16(3);
#undef MFMA16
  }

  // epilogue. C/D layout: col = lane&15, row = (lane>>4)*4 + q  [m89/m91]
  const int crow0 = brow + wm * 128;
  const int ccol0 = bcol + wn * 64;
  if (MODE == 0) {
    const int section = bcol >> 11;
    bf16_t* dst = (section == 0) ? Oi : ((section == 1) ? Ot : Oo);
#pragma unroll
    for (int mi = 0; mi < 8; ++mi)
#pragma unroll
      for (int ni = 0; ni < 4; ++ni) {
        int gcol = ccol0 + ni * 16 + (lane & 15);
        int col = gcol & 2047;
        float bv = bias[gcol];
#pragma unroll
        for (int qq = 0; qq < 4; ++qq) {
          int row = crow0 + mi * 16 + (lane >> 4) * 4 + qq;
          float v = acc[mi][ni][qq] + bv;
          float aout;
          if (section == 0)      aout = 1.f / (1.f + __expf(-v));
          else if (section == 1) aout = tanhf(v);
          else                   aout = v;
          dst[(size_t)row * HIDDEN + col] = (bf16_t)aout;
        }
      }
  } else {
#pragma unroll
    for (int mi = 0; mi < 8; ++mi)
#pragma unroll
      for (int ni = 0; ni < 4; ++ni) {
        int col = ccol0 + ni * 16 + (lane & 15);
        float bv = bias[col];
#pragma unroll
        for (int qq = 0; qq < 4; ++qq) {
          int row = crow0 + mi * 16 + (lane >> 4) * 4 + qq;
          Of[(size_t)row * DIM + col] = acc[mi][ni][qq] + bv;
        }
      }
  }
}

// ---------------- segmented scan (x4-channel vectorized, G13) ----------------
// Channel group ch=4*chg..+3 shares head (= ch>>7; 4 | 128).
__global__ void scan_pass1(const float* __restrict__ fg, const bf16_t* __restrict__ gi,
                           const bf16_t* __restrict__ gt, float* __restrict__ cend,
                           float* __restrict__ pseg) {
  int bx = blockIdx.x;
  int gblk = bx & 1, seg = (bx >> 1) & 63, b = bx >> 7;
  int chg = gblk * 256 + threadIdx.x;      // 0..511
  int ch = chg * 4;
  int head = ch >> 7;
  float c0 = 0.f, c1 = 0.f, c2 = 0.f, c3 = 0.f, P = 1.f;
  size_t t0 = (size_t)b * SEQ + (size_t)seg * SEGLEN;
  for (int tt = 0; tt < SEGLEN; ++tt) {
    size_t bt = t0 + tt;
    float f = fg[bt * NHEADS + head];
    bf16x4_t iv = *reinterpret_cast<const bf16x4_t*>(&gi[bt * HIDDEN + ch]);
    bf16x4_t tv = *reinterpret_cast<const bf16x4_t*>(&gt[bt * HIDDEN + ch]);
    c0 = fmaf(f, c0, (float)iv[0] * (float)tv[0]);
    c1 = fmaf(f, c1, (float)iv[1] * (float)tv[1]);
    c2 = fmaf(f, c2, (float)iv[2] * (float)tv[2]);
    c3 = fmaf(f, c3, (float)iv[3] * (float)tv[3]);
    P *= f;
  }
  size_t o = ((size_t)b * NSEG + seg) * HIDDEN + ch;
  *reinterpret_cast<float4*>(&cend[o]) = make_float4(c0, c1, c2, c3);
  *reinterpret_cast<float4*>(&pseg[o]) = make_float4(P, P, P, P);
}

__global__ void scan_pass2(const float* __restrict__ cend, const float* __restrict__ pseg,
                           float* __restrict__ cin) {
  int idx = blockIdx.x * 256 + threadIdx.x;  // 4096
  int b = idx >> 11, ch = idx & 2047;
  float C = 0.f;
  for (int s = 0; s < NSEG; ++s) {
    size_t o = ((size_t)b * NSEG + s) * HIDDEN + ch;
    cin[o] = C;
    C = cend[o] + pseg[o] * C;
  }
}

__global__ void scan_pass3(const float* __restrict__ fg, const bf16_t* __restrict__ gi,
                           const bf16_t* __restrict__ gt, const bf16_t* __restrict__ go,
                           const float* __restrict__ cin, bf16_t* __restrict__ h) {
  int bx = blockIdx.x;
  int gblk = bx & 1, seg = (bx >> 1) & 63, b = bx >> 7;
  int chg = gblk * 256 + threadIdx.x;
  int ch = chg * 4;
  int head = ch >> 7;
  float4 cv = *reinterpret_cast<const float4*>(&cin[((size_t)b * NSEG + seg) * HIDDEN + ch]);
  float c0 = cv.x, c1 = cv.y, c2 = cv.z, c3 = cv.w;
  size_t t0 = (size_t)b * SEQ + (size_t)seg * SEGLEN;
  for (int tt = 0; tt < SEGLEN; ++tt) {
    size_t bt = t0 + tt;
    float f = fg[bt * NHEADS + head];
    bf16x4_t iv = *reinterpret_cast<const bf16x4_t*>(&gi[bt * HIDDEN + ch]);
    bf16x4_t tv = *reinterpret_cast<const bf16x4_t*>(&gt[bt * HIDDEN + ch]);
    bf16x4_t ov = *reinterpret_cast<const bf16x4_t*>(&go[bt * HIDDEN + ch]);
    c0 = fmaf(f, c0, (float)iv[0] * (float)tv[0]);
    c1 = fmaf(f, c1, (float)iv[1] * (float)tv[1]);
    c2 = fmaf(f, c2, (float)iv[2] * (float)tv[2]);
    c3 = fmaf(f, c3, (float)iv[3] * (float)tv[3]);
    bf16x4_t hv;
    hv[0] = (bf16_t)((float)ov[0] * tanhf(c0));
    hv[1] = (bf16_t)((float)ov[1] * tanhf(c1));
    hv[2] = (bf16_t)((float)ov[2] * tanhf(c2));
    hv[3] = (bf16_t)((float)ov[3] * tanhf(c3));
    *reinterpret_cast<bf16x4_t*>(&h[bt * HIDDEN + ch]) = hv;
  }
}

extern "C" void kernel_launch(void* const* d_in, const int* in_sizes, int n_in,
                              void* d_out, int out_size, void* d_ws, size_t ws_size,
                              hipStream_t stream) {
  const float* x  = (const float*)d_in[0];
  const float* Wg = (const float*)d_in[1];
  const float* bg = (const float*)d_in[2];
  const float* Wo = (const float*)d_in[3];
  const float* bo = (const float*)d_in[4];
  float* out = (float*)d_out;

  char* ws = (char*)d_ws;
  size_t off = 0;
  auto alloc = [&](size_t bytes) -> void* {
    void* p = ws + off;
    off += (bytes + 255) & ~(size_t)255;
    return p;
  };
  bf16_t* xb   = (bf16_t*)alloc((size_t)BT * DIM * 2);
  bf16_t* wgb  = (bf16_t*)alloc((size_t)N_GATE * DIM * 2);
  bf16_t* wob  = (bf16_t*)alloc((size_t)DIM * HIDDEN * 2);
  float*  fg   = (float*)alloc((size_t)BT * NHEADS * 4);
  bf16_t* gi   = (bf16_t*)alloc((size_t)BT * HIDDEN * 2);
  bf16_t* gt   = (bf16_t*)alloc((size_t)BT * HIDDEN * 2);
  bf16_t* go   = (bf16_t*)alloc((size_t)BT * HIDDEN * 2);
  bf16_t* hbuf = (bf16_t*)alloc((size_t)BT * HIDDEN * 2);
  float*  cend = (float*)alloc((size_t)BATCH * NSEG * HIDDEN * 4);
  float*  pseg = (float*)alloc((size_t)BATCH * NSEG * HIDDEN * 4);
  float*  cin  = (float*)alloc((size_t)BATCH * NSEG * HIDDEN * 4);
  (void)ws_size; (void)in_sizes; (void)n_in; (void)out_size;

  // merged weight converts (x-convert is fused into fgate_cvt)
  {
    int n4a = N_GATE * DIM / 4;           // 3,145,728
    int n4b = DIM * HIDDEN / 4;           // 1,048,576
    int nthread = n4a + n4b;
    cvt_weights<<<(nthread + 255) / 256, 256, 0, stream>>>(
        Wg + (size_t)NHEADS * DIM, wgb, n4a, Wo, wob, n4b);
  }

  // f gate in fp32 + fused x -> bf16
  fgate_cvt<<<(BT * NHEADS) / 256, 256, 0, stream>>>(x, Wg, bg, fg, xb);

  // gates GEMM: M=8192, N=6144, K=2048 -> 32x24 = 768 tiles
  gemm256<0><<<768, 512, 0, stream>>>(xb, wgb, bg + NHEADS, gi, gt, go, nullptr, 24);

  // segmented scan (x4-channel vectorized)
  scan_pass1<<<BATCH * NSEG * 2, 256, 0, stream>>>(fg, gi, gt, cend, pseg);
  scan_pass2<<<BATCH * HIDDEN / 256, 256, 0, stream>>>(cend, pseg, cin);
  scan_pass3<<<BATCH * NSEG * 2, 256, 0, stream>>>(fg, gi, gt, go, cin, hbuf);

  // output GEMM: M=8192, N=2048, K=2048 -> 32x8 = 256 tiles
  gemm256<1><<<256, 512, 0, stream>>>(hbuf, wob, bo, nullptr, nullptr, nullptr, out, 8);
}